// Round 7
// baseline (330.970 us; speedup 1.0000x reference)
//
#include <hip/hip_runtime.h>

#define D 64
#define CAP 64   // max in-degree slots per node; deg ~ Poisson(16), P(>64) ~ 1e-19

// ---------------------------------------------------------------------------
// Round-12: occupancy fix for the gather kernel.
// Round-11 counters: gather 189us @ occ 42%, VALU 22%, HBM 16% -> still
// latency-bound; cap = 32KB LDS per 4-wave block (5 blocks/CU = 20 waves =
// 62.5% max). Fix: 512-thread blocks (8 waves, 8 nodes/block) share the same
// 32KB -> wave cap binds instead: 4 blocks x 8 waves = 32 waves/CU = 100%.
// Everything else unchanged (exact block->(type,chunk) map, 16-deep gather
// unroll, LDS weights, fused pack+bucket).
// Same arithmetic order -> absmax 0.125.
// ---------------------------------------------------------------------------

__device__ __forceinline__ unsigned bf16rne(float f) {
    unsigned u = __float_as_uint(f);
    return (u + 0x7fffu + ((u >> 16) & 1u)) >> 16;   // round-to-nearest-even
}
__device__ __forceinline__ float bf_lo(unsigned w) { return __uint_as_float(w << 16); }
__device__ __forceinline__ float bf_hi(unsigned w) { return __uint_as_float(w & 0xffff0000u); }

__device__ __forceinline__ void acc8(float (&a)[8], const uint4& v) {
    a[0] += bf_lo(v.x); a[1] += bf_hi(v.x);
    a[2] += bf_lo(v.y); a[3] += bf_hi(v.y);
    a[4] += bf_lo(v.z); a[5] += bf_hi(v.z);
    a[6] += bf_lo(v.w); a[7] += bf_hi(v.w);
}

// pack (1.6M threads' worth) + edge bucketing (800K) + type bucketing (50K),
// fused: independent jobs on independent pipes. counts must be pre-zeroed.
__global__ __launch_bounds__(256) void k_pack_bucket(
    const float* __restrict__ x, const float* __restrict__ vec,
    const int* __restrict__ src, const int* __restrict__ dst,
    const int* __restrict__ node_type,
    uint4* __restrict__ packed,
    int* __restrict__ counts,   // [n_nodes] degree hist; cursor t at n_nodes+32*t
    int* __restrict__ slots, int* __restrict__ typed,
    int n_edges, int n_nodes)
{
    int idx = blockIdx.x * 256 + threadIdx.x;
    int lane = threadIdx.x & 63;

    // ---- node -> type bucketing, wave-aggregated (1 atomic per type/wave) ----
    bool nvalid = (idx < n_nodes);
    int t = nvalid ? node_type[idx] : -1;
#pragma unroll
    for (int tt = 0; tt < 4; ++tt) {
        unsigned long long m = __ballot(t == tt);
        if (t == tt) {
            int pos = __popcll(m & ((1ull << lane) - 1ull));
            int base = 0;
            if (pos == 0) base = atomicAdd(&counts[n_nodes + 32 * tt], (int)__popcll(m));
            int leader = __ffsll((long long)m) - 1;
            base = __shfl(base, leader);
            typed[(size_t)tt * n_nodes + base + pos] = idx;
        }
    }

    // ---- per-dst slot lists (atomic-latency chain, issued early) ----
    if (idx < n_edges) {
        int d = dst[idx];
        int slot = atomicAdd(&counts[d], 1);
        if (slot < CAP) slots[(size_t)d * CAP + slot] = src[idx];
    }

    // ---- bf16 pack: one uint4 (8 elems) per thread, BW-bound ----
    if (idx >= n_nodes * 32) return;
    int n = idx >> 5, j = idx & 31;
    int ei = j * 8;                               // element index within 512B row
    const float* sp = (ei < 64) ? (x + (size_t)n * 64 + ei)
                                : (vec + (size_t)n * 192 + (ei - 64));
    float4 f0 = *(const float4*)sp;
    float4 f1 = *(const float4*)(sp + 4);
    uint4 w;
    w.x = bf16rne(f0.x) | (bf16rne(f0.y) << 16);
    w.y = bf16rne(f0.z) | (bf16rne(f0.w) << 16);
    w.z = bf16rne(f1.x) | (bf16rne(f1.y) << 16);
    w.w = bf16rne(f1.z) | (bf16rne(f1.w) << 16);
    packed[idx] = w;
}

__global__ __launch_bounds__(512) void k_gather_project_lds(
    const uint4* __restrict__ packed,
    const float* __restrict__ W_s, const float* __restrict__ W_v,
    const int* __restrict__ counts, const int* __restrict__ slots,
    const int* __restrict__ typed,
    float* __restrict__ out_s, float* __restrict__ out_v, int n_nodes)
{
    __shared__ float lws[D * D];   // 16 KB: this type's W_s
    __shared__ float lwv[D * D];   // 16 KB: this type's W_v

    // exact block -> (type, chunk) mapping from the 4 type counters: no idle
    // blocks. 8 nodes per block (8 waves x 1 node).
    int c0 = counts[n_nodes], c1 = counts[n_nodes + 32];
    int c2 = counts[n_nodes + 64], c3 = counts[n_nodes + 96];
    int nb0 = (c0 + 7) >> 3, nb1 = (c1 + 7) >> 3, nb2 = (c2 + 7) >> 3, nb3 = (c3 + 7) >> 3;
    int b = blockIdx.x, t, chunk, cnt_t;
    if      (b < nb0)                   { t = 0; chunk = b;                   cnt_t = c0; }
    else if (b < nb0 + nb1)             { t = 1; chunk = b - nb0;             cnt_t = c1; }
    else if (b < nb0 + nb1 + nb2)       { t = 2; chunk = b - nb0 - nb1;       cnt_t = c2; }
    else if (b < nb0 + nb1 + nb2 + nb3) { t = 3; chunk = b - nb0 - nb1 - nb2; cnt_t = c3; }
    else return;                                  // uniform: whole block exits

    // ---- stage this type's weights to LDS: 4 float4 loads per thread ----
    {
        const float4* gs = (const float4*)(W_s + (size_t)t * D * D);
        const float4* gv = (const float4*)(W_v + (size_t)t * D * D);
        float4* ls = (float4*)lws;
        float4* lv = (float4*)lwv;
        for (int k = threadIdx.x; k < (D * D) / 4; k += 512) {
            ls[k] = gs[k];
            lv[k] = gv[k];
        }
    }
    __syncthreads();                              // all threads of block reach this

    int wv = threadIdx.x >> 6, lane = threadIdx.x & 63;
    int j = chunk * 8 + wv;                       // 1 node per wave
    if (j >= cnt_t) return;                       // after barrier: safe

    int n = typed[(size_t)t * n_nodes + j];       // wave-uniform
    int cnt = counts[n]; if (cnt > CAP) cnt = CAP;
    int half = lane >> 5, hl = lane & 31;
    int idx = slots[(size_t)n * CAP + lane];      // one coalesced 256B wave load

    float a[8];
#pragma unroll
    for (int i = 0; i < 8; ++i) a[i] = 0.f;

    int k = 0;
    // 16 edges per iteration: 8 independent 512B loads in flight per half-wave
    for (; k + 16 <= cnt; k += 16) {
        int s[8]; uint4 w[8];
#pragma unroll
        for (int u = 0; u < 8; ++u) s[u] = __shfl(idx, k + 2 * u + half);
#pragma unroll
        for (int u = 0; u < 8; ++u) w[u] = packed[(size_t)s[u] * 32 + hl];
#pragma unroll
        for (int u = 0; u < 8; ++u) acc8(a, w[u]);
    }
    for (; k + 8 <= cnt; k += 8) {
        int s0 = __shfl(idx, k     + half);
        int s1 = __shfl(idx, k + 2 + half);
        int s2 = __shfl(idx, k + 4 + half);
        int s3 = __shfl(idx, k + 6 + half);
        uint4 w0 = packed[(size_t)s0 * 32 + hl];
        uint4 w1 = packed[(size_t)s1 * 32 + hl];
        uint4 w2 = packed[(size_t)s2 * 32 + hl];
        uint4 w3 = packed[(size_t)s3 * 32 + hl];
        acc8(a, w0); acc8(a, w1); acc8(a, w2); acc8(a, w3);
    }
    for (; k + 2 <= cnt; k += 2) {
        int s = __shfl(idx, k + half);
        uint4 w = packed[(size_t)s * 32 + hl];
        acc8(a, w);
    }
    if (k < cnt) {                       // odd leftover: half 0 only
        int s = __shfl(idx, k);
        if (half == 0) { uint4 w = packed[(size_t)s * 32 + hl]; acc8(a, w); }
    }
    // combine half-waves; both halves end with the full sums
#pragma unroll
    for (int i = 0; i < 8; ++i) a[i] += __shfl_xor(a[i], 32);

    // Projection: elem g = c*64+i lives in lane c*8 + (i>>3), reg i&7
    // (mapping verified round 3). Weights from LDS (2 lanes/bank = free).
    float ys = 0.f, y0 = 0.f, y1 = 0.f, y2 = 0.f;
#pragma unroll
    for (int i = 0; i < D; ++i) {
        float as  = __shfl(a[i & 7],      (i >> 3));
        float av0 = __shfl(a[i & 7],  8 + (i >> 3));
        float av1 = __shfl(a[i & 7], 16 + (i >> 3));
        float av2 = __shfl(a[i & 7], 24 + (i >> 3));
        float wsi = lws[i * D + lane];
        float wvi = lwv[i * D + lane];
        ys = fmaf(as,  wsi, ys);
        y0 = fmaf(av0, wvi, y0);
        y1 = fmaf(av1, wvi, y1);
        y2 = fmaf(av2, wvi, y2);
    }
    out_s[(size_t)n * D + lane] = ys;
    float* ov = out_v + (size_t)n * 3 * D;
    ov[lane] = y0; ov[D + lane] = y1; ov[2 * D + lane] = y2;
}

// ====================== round-2 fallback (proven) ==========================
__global__ __launch_bounds__(256) void k_hist(
    const int* __restrict__ dst, int* __restrict__ counts,
    int* __restrict__ pos, int n_edges)
{
    int e = blockIdx.x * 256 + threadIdx.x;
    if (e < n_edges) pos[e] = atomicAdd(&counts[dst[e]], 1);
}
__global__ __launch_bounds__(256) void k_base(
    const int* __restrict__ counts, int* __restrict__ base,
    int* __restrict__ cursor, int n_nodes)
{
    int n = blockIdx.x * 256 + threadIdx.x;
    if (n < n_nodes) base[n] = atomicAdd(cursor, counts[n]);
}
__global__ __launch_bounds__(256) void k_fill(
    const int* __restrict__ src, const int* __restrict__ dst,
    const int* __restrict__ base, const int* __restrict__ pos,
    int* __restrict__ csr, int n_edges)
{
    int e = blockIdx.x * 256 + threadIdx.x;
    if (e < n_edges) csr[base[dst[e]] + pos[e]] = src[e];
}
__global__ __launch_bounds__(256) void k_gather_project_f32(
    const float* __restrict__ x, const float* __restrict__ vec,
    const int* __restrict__ node_type,
    const float* __restrict__ W_s, const float* __restrict__ W_v,
    const int* __restrict__ counts, const int* __restrict__ base,
    const int* __restrict__ csr,
    float* __restrict__ out_s, float* __restrict__ out_v, int n_nodes)
{
    __shared__ float agg[4][4 * D];
    int wave = threadIdx.x >> 6, lane = threadIdx.x & 63;
    int ch = lane >> 4, q = lane & 15;
    int n = blockIdx.x * 4 + wave;
    int cnt = 0, b = 0, t = 0;
    if (n < n_nodes) { cnt = counts[n]; b = base[n]; t = node_type[n]; }
    bool isx = (ch == 0);
    const float4* bp = isx ? (const float4*)x : (const float4*)vec;
    int stride4 = isx ? 16 : 48;
    int off4 = isx ? q : (ch - 1) * 16 + q;
    float4 acc = make_float4(0.f, 0.f, 0.f, 0.f);
    for (int k = 0; k < cnt; ++k) {
        int s = csr[b + k];
        float4 r = bp[(size_t)s * stride4 + off4];
        acc.x += r.x; acc.y += r.y; acc.z += r.z; acc.w += r.w;
    }
    *(float4*)&agg[wave][ch * D + q * 4] = acc;
    __syncthreads();
    if (n >= n_nodes) return;
    const float* Ws = W_s + (size_t)t * D * D;
    const float* Wv = W_v + (size_t)t * D * D;
    const float* a0 = &agg[wave][0];
    float ys = 0.f, y0 = 0.f, y1 = 0.f, y2 = 0.f;
#pragma unroll 8
    for (int i = 0; i < D; ++i) {
        float wsi = Ws[i * D + lane], wvi = Wv[i * D + lane];
        ys = fmaf(a0[i], wsi, ys);
        y0 = fmaf(a0[D + i], wvi, y0);
        y1 = fmaf(a0[2 * D + i], wvi, y1);
        y2 = fmaf(a0[3 * D + i], wvi, y2);
    }
    out_s[(size_t)n * D + lane] = ys;
    float* ov = out_v + (size_t)n * 3 * D;
    ov[lane] = y0; ov[D + lane] = y1; ov[2 * D + lane] = y2;
}

extern "C" void kernel_launch(void* const* d_in, const int* in_sizes, int n_in,
                              void* d_out, int out_size, void* d_ws, size_t ws_size,
                              hipStream_t stream) {
    const float* x         = (const float*)d_in[0];
    const float* vec       = (const float*)d_in[1];
    const int*   node_type = (const int*)d_in[2];
    const int*   src       = (const int*)d_in[3];
    const int*   dst       = (const int*)d_in[4];
    const float* W_s       = (const float*)d_in[5];
    const float* W_v       = (const float*)d_in[6];

    int n_nodes = in_sizes[2];
    int n_edges = in_sizes[3];

    float* out_s = (float*)d_out;
    float* out_v = out_s + (size_t)n_nodes * D;

    int eb = (n_edges + 255) / 256;

    // fast path ws layout:
    // [packed uint4 N*32][slots int N*CAP][counts int N+128][typed int 4N]
    size_t packed_bytes = (size_t)n_nodes * 32 * sizeof(uint4);     // 25.6 MB
    size_t slots_bytes  = (size_t)n_nodes * CAP * sizeof(int);      // 12.8 MB
    size_t counts_bytes = ((size_t)n_nodes + 128) * sizeof(int);    //  0.2 MB
    size_t typed_bytes  = (size_t)n_nodes * 4 * sizeof(int);        //  0.8 MB
    size_t need_fast = packed_bytes + slots_bytes + counts_bytes + typed_bytes;

    if (ws_size >= need_fast) {
        uint4* packed = (uint4*)d_ws;
        int*   slots  = (int*)((char*)d_ws + packed_bytes);
        int*   counts = (int*)((char*)d_ws + packed_bytes + slots_bytes);
        int*   typed  = (int*)((char*)d_ws + packed_bytes + slots_bytes + counts_bytes);

        (void)hipMemsetAsync(counts, 0, counts_bytes, stream);

        // fused kernel grid must cover pack (N*32 threads); bucket/typed
        // parts are guarded subsets of the same index space.
        int fb = (n_nodes * 32 + 255) / 256;
        k_pack_bucket<<<fb, 256, 0, stream>>>(
            x, vec, src, dst, node_type, packed, counts, slots, typed,
            n_edges, n_nodes);

        // exact-cover grid: sum over types of ceil(cnt_t/8) <= N/8 + 4
        int gb = n_nodes / 8 + 4;
        k_gather_project_lds<<<gb, 512, 0, stream>>>(
            packed, W_s, W_v, counts, slots, typed, out_s, out_v, n_nodes);
        return;
    }

    // round-2 fallback: [cursor 1][counts N][base N][pos E][csr E]
    int* cursor = (int*)d_ws;
    int* counts = cursor + 1;
    int* base   = counts + n_nodes;
    int* pos    = base + n_nodes;
    int* csr    = pos + n_edges;
    int nb = (n_nodes + 255) / 256;
    int nb4 = (n_nodes + 3) / 4;
    (void)hipMemsetAsync(cursor, 0, (size_t)(1 + n_nodes) * sizeof(int), stream);
    k_hist<<<eb, 256, 0, stream>>>(dst, counts, pos, n_edges);
    k_base<<<nb, 256, 0, stream>>>(counts, base, cursor, n_nodes);
    k_fill<<<eb, 256, 0, stream>>>(src, dst, base, pos, csr, n_edges);
    k_gather_project_f32<<<nb4, 256, 0, stream>>>(
        x, vec, node_type, W_s, W_v, counts, base, csr, out_s, out_v, n_nodes);
}

// Round 8
// 293.424 us; speedup vs baseline: 1.1280x; 1.1280x over previous
//
#include <hip/hip_runtime.h>

#define D 64
#define CAP 64   // max in-degree slots per node; deg ~ Poisson(16), P(>64) ~ 1e-19

// ---------------------------------------------------------------------------
// Round-13: consolidation. The r7-r12 LDS/type-sort detour never beat the
// simple r6 structure (164us @ occ 83% vs 189us @ occ 45%; two different
// LDS configs gave identical dur -> occupancy theory dead, memory path is
// the bound). Revert to r6 skeleton, add only mechanistically-clear deltas:
//  - k_gather_project: 16-edge unroll (8 gather loads in flight/wave, 2x r6)
//    + projection weight loads batched 16-at-a-time (r6's VGPR=32 allowed
//    ~4 in flight; this was the round-1 diagnosed stall).
//  - k_pack_bucket: type-ballot dropped entirely (weights are L2-hot for all
//    4 types; type-sorting bought nothing); pack's 2x16B loads issued BEFORE
//    the dst->atomic->store chain so they hide under atomic latency.
// Same arithmetic order as r6 -> absmax 0.125.
// ---------------------------------------------------------------------------

__device__ __forceinline__ unsigned bf16rne(float f) {
    unsigned u = __float_as_uint(f);
    return (u + 0x7fffu + ((u >> 16) & 1u)) >> 16;   // round-to-nearest-even
}
__device__ __forceinline__ float bf_lo(unsigned w) { return __uint_as_float(w << 16); }
__device__ __forceinline__ float bf_hi(unsigned w) { return __uint_as_float(w & 0xffff0000u); }

__device__ __forceinline__ void acc8(float (&a)[8], const uint4& v) {
    a[0] += bf_lo(v.x); a[1] += bf_hi(v.x);
    a[2] += bf_lo(v.y); a[3] += bf_hi(v.y);
    a[4] += bf_lo(v.z); a[5] += bf_hi(v.z);
    a[6] += bf_lo(v.w); a[7] += bf_hi(v.w);
}

// pack (N*32 threads) + edge bucketing (E threads), fused. counts pre-zeroed.
// Pack loads are issued FIRST so they are in flight during the bucket's
// dependent chain (dst load -> atomicAdd -> slot store).
__global__ __launch_bounds__(256) void k_pack_bucket(
    const float* __restrict__ x, const float* __restrict__ vec,
    const int* __restrict__ src, const int* __restrict__ dst,
    uint4* __restrict__ packed,
    int* __restrict__ counts,          // [n_nodes] degree histogram
    int* __restrict__ slots, int n_edges, int n_nodes)
{
    int idx = blockIdx.x * 256 + threadIdx.x;

    // ---- issue pack loads early (no dependences) ----
    bool dopack = (idx < n_nodes * 32);
    float4 f0, f1;
    if (dopack) {
        int n = idx >> 5, j = idx & 31;
        int ei = j * 8;                           // element index within 256-row
        const float* sp = (ei < 64) ? (x + (size_t)n * 64 + ei)
                                    : (vec + (size_t)n * 192 + (ei - 64));
        f0 = *(const float4*)sp;
        f1 = *(const float4*)(sp + 4);
    }

    // ---- per-dst slot lists (latency chain overlapped with pack loads) ----
    if (idx < n_edges) {
        int d = dst[idx];
        int s = src[idx];
        int slot = atomicAdd(&counts[d], 1);
        if (slot < CAP) slots[(size_t)d * CAP + slot] = s;
    }

    // ---- finish pack: f32 -> bf16 pair pack ----
    if (dopack) {
        uint4 w;
        w.x = bf16rne(f0.x) | (bf16rne(f0.y) << 16);
        w.y = bf16rne(f0.z) | (bf16rne(f0.w) << 16);
        w.z = bf16rne(f1.x) | (bf16rne(f1.y) << 16);
        w.w = bf16rne(f1.z) | (bf16rne(f1.w) << 16);
        packed[idx] = w;
    }
}

__global__ __launch_bounds__(256) void k_gather_project(
    const uint4* __restrict__ packed, const int* __restrict__ node_type,
    const float* __restrict__ W_s, const float* __restrict__ W_v,
    const int* __restrict__ counts, const int* __restrict__ slots,
    float* __restrict__ out_s, float* __restrict__ out_v, int n_nodes)
{
    int wave = threadIdx.x >> 6;
    int lane = threadIdx.x & 63;
    int n = blockIdx.x * 4 + wave;
    if (n >= n_nodes) return;
    int half = lane >> 5, hl = lane & 31;

    int t = node_type[n];                        // issued early, used late
    int cnt = counts[n]; if (cnt > CAP) cnt = CAP;
    // ALL slot indices in one coalesced 256B wave load
    int myidx = slots[(size_t)n * CAP + lane];

    float a[8];
#pragma unroll
    for (int i = 0; i < 8; ++i) a[i] = 0.f;

    int k = 0;
    // 16 edges per iteration: 8 independent 512B loads in flight per half-wave
    for (; k + 16 <= cnt; k += 16) {
        int s[8]; uint4 w[8];
#pragma unroll
        for (int u = 0; u < 8; ++u) s[u] = __shfl(myidx, k + 2 * u + half);
#pragma unroll
        for (int u = 0; u < 8; ++u) w[u] = packed[(size_t)s[u] * 32 + hl];
#pragma unroll
        for (int u = 0; u < 8; ++u) acc8(a, w[u]);
    }
    for (; k + 8 <= cnt; k += 8) {
        int s0 = __shfl(myidx, k     + half);
        int s1 = __shfl(myidx, k + 2 + half);
        int s2 = __shfl(myidx, k + 4 + half);
        int s3 = __shfl(myidx, k + 6 + half);
        uint4 w0 = packed[(size_t)s0 * 32 + hl];
        uint4 w1 = packed[(size_t)s1 * 32 + hl];
        uint4 w2 = packed[(size_t)s2 * 32 + hl];
        uint4 w3 = packed[(size_t)s3 * 32 + hl];
        acc8(a, w0); acc8(a, w1); acc8(a, w2); acc8(a, w3);
    }
    for (; k + 2 <= cnt; k += 2) {
        int s = __shfl(myidx, k + half);
        uint4 w = packed[(size_t)s * 32 + hl];
        acc8(a, w);
    }
    if (k < cnt) {                       // odd leftover: half 0 only
        int s = __shfl(myidx, k);
        if (half == 0) { uint4 w = packed[(size_t)s * 32 + hl]; acc8(a, w); }
    }
    // combine half-waves; both halves end with the full sums
#pragma unroll
    for (int i = 0; i < 8; ++i) a[i] += __shfl_xor(a[i], 32);

    // Projection: elem g = c*64+i lives in lane c*8 + (i>>3), reg i&7
    // (mapping verified round 3). Weight loads batched 16-at-a-time so the
    // compiler keeps them in flight (r6 had only ~4 with VGPR=32).
    // i = g*8+u  ->  i&7 = u, i>>3 = g  (identical arithmetic order to r6).
    const float* Ws = W_s + (size_t)t * D * D;
    const float* Wv = W_v + (size_t)t * D * D;
    float ys = 0.f, y0 = 0.f, y1 = 0.f, y2 = 0.f;
#pragma unroll
    for (int g = 0; g < 8; ++g) {
        float ws[8], wv[8];
#pragma unroll
        for (int u = 0; u < 8; ++u) {
            ws[u] = Ws[(g * 8 + u) * D + lane];  // 256B coalesced, L2-resident
            wv[u] = Wv[(g * 8 + u) * D + lane];
        }
#pragma unroll
        for (int u = 0; u < 8; ++u) {
            float as  = __shfl(a[u],      g);
            float av0 = __shfl(a[u],  8 + g);
            float av1 = __shfl(a[u], 16 + g);
            float av2 = __shfl(a[u], 24 + g);
            ys = fmaf(as,  ws[u], ys);
            y0 = fmaf(av0, wv[u], y0);
            y1 = fmaf(av1, wv[u], y1);
            y2 = fmaf(av2, wv[u], y2);
        }
    }
    out_s[(size_t)n * D + lane] = ys;
    float* ov = out_v + (size_t)n * 3 * D;
    ov[lane] = y0; ov[D + lane] = y1; ov[2 * D + lane] = y2;
}

// ====================== round-2 fallback (proven) ==========================
__global__ __launch_bounds__(256) void k_hist(
    const int* __restrict__ dst, int* __restrict__ counts,
    int* __restrict__ pos, int n_edges)
{
    int e = blockIdx.x * 256 + threadIdx.x;
    if (e < n_edges) pos[e] = atomicAdd(&counts[dst[e]], 1);
}
__global__ __launch_bounds__(256) void k_base(
    const int* __restrict__ counts, int* __restrict__ base,
    int* __restrict__ cursor, int n_nodes)
{
    int n = blockIdx.x * 256 + threadIdx.x;
    if (n < n_nodes) base[n] = atomicAdd(cursor, counts[n]);
}
__global__ __launch_bounds__(256) void k_fill(
    const int* __restrict__ src, const int* __restrict__ dst,
    const int* __restrict__ base, const int* __restrict__ pos,
    int* __restrict__ csr, int n_edges)
{
    int e = blockIdx.x * 256 + threadIdx.x;
    if (e < n_edges) csr[base[dst[e]] + pos[e]] = src[e];
}
__global__ __launch_bounds__(256) void k_gather_project_f32(
    const float* __restrict__ x, const float* __restrict__ vec,
    const int* __restrict__ node_type,
    const float* __restrict__ W_s, const float* __restrict__ W_v,
    const int* __restrict__ counts, const int* __restrict__ base,
    const int* __restrict__ csr,
    float* __restrict__ out_s, float* __restrict__ out_v, int n_nodes)
{
    __shared__ float agg[4][4 * D];
    int wave = threadIdx.x >> 6, lane = threadIdx.x & 63;
    int ch = lane >> 4, q = lane & 15;
    int n = blockIdx.x * 4 + wave;
    int cnt = 0, b = 0, t = 0;
    if (n < n_nodes) { cnt = counts[n]; b = base[n]; t = node_type[n]; }
    bool isx = (ch == 0);
    const float4* bp = isx ? (const float4*)x : (const float4*)vec;
    int stride4 = isx ? 16 : 48;
    int off4 = isx ? q : (ch - 1) * 16 + q;
    float4 acc = make_float4(0.f, 0.f, 0.f, 0.f);
    for (int k = 0; k < cnt; ++k) {
        int s = csr[b + k];
        float4 r = bp[(size_t)s * stride4 + off4];
        acc.x += r.x; acc.y += r.y; acc.z += r.z; acc.w += r.w;
    }
    *(float4*)&agg[wave][ch * D + q * 4] = acc;
    __syncthreads();
    if (n >= n_nodes) return;
    const float* Ws = W_s + (size_t)t * D * D;
    const float* Wv = W_v + (size_t)t * D * D;
    const float* a0 = &agg[wave][0];
    float ys = 0.f, y0 = 0.f, y1 = 0.f, y2 = 0.f;
#pragma unroll 8
    for (int i = 0; i < D; ++i) {
        float wsi = Ws[i * D + lane], wvi = Wv[i * D + lane];
        ys = fmaf(a0[i], wsi, ys);
        y0 = fmaf(a0[D + i], wvi, y0);
        y1 = fmaf(a0[2 * D + i], wvi, y1);
        y2 = fmaf(a0[3 * D + i], wvi, y2);
    }
    out_s[(size_t)n * D + lane] = ys;
    float* ov = out_v + (size_t)n * 3 * D;
    ov[lane] = y0; ov[D + lane] = y1; ov[2 * D + lane] = y2;
}

extern "C" void kernel_launch(void* const* d_in, const int* in_sizes, int n_in,
                              void* d_out, int out_size, void* d_ws, size_t ws_size,
                              hipStream_t stream) {
    const float* x         = (const float*)d_in[0];
    const float* vec       = (const float*)d_in[1];
    const int*   node_type = (const int*)d_in[2];
    const int*   src       = (const int*)d_in[3];
    const int*   dst       = (const int*)d_in[4];
    const float* W_s       = (const float*)d_in[5];
    const float* W_v       = (const float*)d_in[6];

    int n_nodes = in_sizes[2];
    int n_edges = in_sizes[3];

    float* out_s = (float*)d_out;
    float* out_v = out_s + (size_t)n_nodes * D;

    int eb = (n_edges + 255) / 256;

    // fast path ws layout: [packed uint4 N*32][slots int N*CAP][counts int N]
    size_t packed_bytes = (size_t)n_nodes * 32 * sizeof(uint4);   // 25.6 MB
    size_t slots_bytes  = (size_t)n_nodes * CAP * sizeof(int);    // 12.8 MB
    size_t counts_bytes = (size_t)n_nodes * sizeof(int);          //  0.2 MB
    size_t need_fast = packed_bytes + slots_bytes + counts_bytes;

    if (ws_size >= need_fast) {
        uint4* packed = (uint4*)d_ws;
        int*   slots  = (int*)((char*)d_ws + packed_bytes);
        int*   counts = (int*)((char*)d_ws + packed_bytes + slots_bytes);

        (void)hipMemsetAsync(counts, 0, counts_bytes, stream);

        // fused grid covers pack (N*32 threads); bucket is a guarded subset.
        int fb = (n_nodes * 32 + 255) / 256;
        k_pack_bucket<<<fb, 256, 0, stream>>>(
            x, vec, src, dst, packed, counts, slots, n_edges, n_nodes);

        int nb4 = (n_nodes + 3) / 4;
        k_gather_project<<<nb4, 256, 0, stream>>>(
            packed, node_type, W_s, W_v, counts, slots, out_s, out_v, n_nodes);
        return;
    }

    // round-2 fallback: [cursor 1][counts N][base N][pos E][csr E]
    int* cursor = (int*)d_ws;
    int* counts = cursor + 1;
    int* base   = counts + n_nodes;
    int* pos    = base + n_nodes;
    int* csr    = pos + n_edges;
    int nb = (n_nodes + 255) / 256;
    int nb4 = (n_nodes + 3) / 4;
    (void)hipMemsetAsync(cursor, 0, (size_t)(1 + n_nodes) * sizeof(int), stream);
    k_hist<<<eb, 256, 0, stream>>>(dst, counts, pos, n_edges);
    k_base<<<nb, 256, 0, stream>>>(counts, base, cursor, n_nodes);
    k_fill<<<eb, 256, 0, stream>>>(src, dst, base, pos, csr, n_edges);
    k_gather_project_f32<<<nb4, 256, 0, stream>>>(
        x, vec, node_type, W_s, W_v, counts, base, csr, out_s, out_v, n_nodes);
}